// Round 1
// baseline (484.194 us; speedup 1.0000x reference)
//
#include <hip/hip_runtime.h>

typedef __attribute__((ext_vector_type(8))) _Float16 half8;
typedef __attribute__((ext_vector_type(4))) _Float16 half4;
typedef __attribute__((ext_vector_type(4))) float floatx4;

#define DEVI __device__ __forceinline__

// ---------------- async global->LDS, 16B/lane ----------------
DEVI void gload_lds16(const _Float16* g, _Float16* l) {
    __builtin_amdgcn_global_load_lds(
        (const __attribute__((address_space(1))) void*)g,
        (__attribute__((address_space(3))) void*)l, 16, 0, 0);
}

#define WAITV(N) asm volatile("s_waitcnt vmcnt(" #N ")" ::: "memory")
#define SBAR() do { __builtin_amdgcn_sched_barrier(0); __builtin_amdgcn_s_barrier(); __builtin_amdgcn_sched_barrier(0); } while (0)

// =====================================================================
// 256x256-tile GEMM, K consumed in 32-wide regions through a 4-slot LDS
// ring (4 x 32 KiB = 128 KiB). 512 threads = 8 waves (2M x 4N); each
// wave owns a 128x64 C sub-tile: acc[8][4] 16x16 frags (128 VGPR).
// Phase(g): stage region g+3 | ds_read frags of region g |
//           vmcnt(8) [region g+1 landed; 8 loads STAY in flight] |
//           s_barrier | setprio(1) 32x MFMA setprio(0) | s_barrier.
// T2 swizzle (conflict-free ds_read_b128) + T3/T4 counted vmcnt + T5.
// =====================================================================

// Slot layout (halfs): A[256 rows][4 chunks of 8] at +0, B same at +8192.
// Chunk p of row r holds global chunk p ^ (r&3): linear LDS dest (required
// by global_load_lds) + inverse-permuted global source; reads apply same XOR.
DEVI void stage_region(const _Float16* __restrict__ A, const _Float16* __restrict__ B,
                       int ldk, _Float16* lds, int g, int tid) {
    _Float16* s = lds + (g & 3) * 16384;
    const int r = tid >> 2;                    // row within 128-row half
    const int c = (tid & 3) ^ (r & 3);         // swizzled source chunk
    const size_t ko = (size_t)(g << 5) + (c << 3);
    gload_lds16(A + (size_t)r * ldk + ko,         s + tid * 8);
    gload_lds16(A + (size_t)(r + 128) * ldk + ko, s + 4096 + tid * 8);
    gload_lds16(B + (size_t)r * ldk + ko,         s + 8192 + tid * 8);
    gload_lds16(B + (size_t)(r + 128) * ldk + ko, s + 12288 + tid * 8);
}

template <int WN>   // 8/4/0: wait for next region, then barrier; -1: final phase
DEVI void phase(const _Float16* lds, int g, floatx4 acc[8][4],
                int arow0, int brow0, int cx)
{
    const _Float16* sa = lds + (g & 3) * 16384;
    const _Float16* sb = sa + 8192;
    half8 a[8], b[4];
#pragma unroll
    for (int ni = 0; ni < 4; ++ni)
        b[ni] = *(const half8*)&sb[(brow0 + ni * 16) * 32 + cx];
#pragma unroll
    for (int mi = 0; mi < 8; ++mi)
        a[mi] = *(const half8*)&sa[(arow0 + mi * 16) * 32 + cx];
    if constexpr (WN == 8) WAITV(8);
    else if constexpr (WN == 4) WAITV(4);
    else if constexpr (WN == 0) WAITV(0);
    if constexpr (WN >= 0) SBAR();
    __builtin_amdgcn_s_setprio(1);
#pragma unroll
    for (int mi = 0; mi < 8; ++mi)
#pragma unroll
        for (int ni = 0; ni < 4; ++ni)
            acc[mi][ni] = __builtin_amdgcn_mfma_f32_16x16x32_f16(a[mi], b[ni], acc[mi][ni], 0, 0, 0);
    __builtin_amdgcn_s_setprio(0);
    if constexpr (WN >= 0) SBAR();
}

// A: 256 rows (M) x K, row stride K; B: 256 rows (N) x K, row stride K.
DEVI void gemm256(const _Float16* __restrict__ A, const _Float16* __restrict__ B,
                  int K, _Float16* lds, floatx4 acc[8][4], int tid)
{
    const int lane = tid & 63, w = tid >> 6;
    const int lr = lane & 15, quad = lane >> 4;
    const int cx = (quad ^ (lr & 3)) << 3;     // row&3 == lr&3 for all frag rows
    const int arow0 = (w >> 2) * 128 + lr;
    const int brow0 = (w & 3) * 64 + lr;
    const int R = K >> 5;                       // regions of 32 K
    stage_region(A, B, K, lds, 0, tid);
    stage_region(A, B, K, lds, 1, tid);
    stage_region(A, B, K, lds, 2, tid);
    WAITV(8);                                   // region 0 landed
    SBAR();
    int g = 0;
    for (; g + 3 < R; ++g) {                    // steady: 8 loads in flight
        stage_region(A, B, K, lds, g + 3, tid);
        phase<8>(lds, g, acc, arow0, brow0, cx);
    }
    phase<4>(lds, g, acc, arow0, brow0, cx); ++g;
    phase<0>(lds, g, acc, arow0, brow0, cx); ++g;
    phase<-1>(lds, g, acc, arow0, brow0, cx);
}

DEVI void zacc(floatx4 acc[8][4]) {
    const floatx4 zf = {0.f, 0.f, 0.f, 0.f};
#pragma unroll
    for (int mi = 0; mi < 8; ++mi)
#pragma unroll
        for (int ni = 0; ni < 4; ++ni) acc[mi][ni] = zf;
}

// ---------------- prep kernels (unchanged) ----------------
__global__ __launch_bounds__(256) void k_cast_x(const float* __restrict__ x, _Float16* __restrict__ xh) {
    size_t i = ((size_t)blockIdx.x * 256 + threadIdx.x) * 8;
    float4 v0 = *(const float4*)(x + i);
    float4 v1 = *(const float4*)(x + i + 4);
    float vv[8] = {v0.x, v0.y, v0.z, v0.w, v1.x, v1.y, v1.z, v1.w};
    half8 h;
#pragma unroll
    for (int j = 0; j < 8; ++j) h[j] = (_Float16)vv[j];
    *(half8*)(xh + i) = h;
}

__global__ __launch_bounds__(256) void k_prep_w(const float* __restrict__ w, _Float16* __restrict__ wh) {
    __shared__ float tile[32][33];
    const int n0 = blockIdx.x * 32, k0 = blockIdx.y * 32;
    const int t = threadIdx.x;
#pragma unroll
    for (int it = 0; it < 4; ++it) {
        int idx = it * 256 + t;
        int kk = idx >> 5, nn = idx & 31;
        tile[kk][nn] = w[(size_t)(k0 + kk) * 3072 + n0 + nn];
    }
    __syncthreads();
#pragma unroll
    for (int it = 0; it < 4; ++it) {
        int idx = it * 256 + t;
        int nn = idx >> 5, kk = idx & 31;
        wh[(size_t)(n0 + nn) * 1024 + k0 + kk] = (_Float16)tile[kk][nn];
    }
}

__global__ __launch_bounds__(256) void k_prep_ow(const float* __restrict__ ow, _Float16* __restrict__ owh) {
    size_t i = ((size_t)blockIdx.x * 256 + threadIdx.x) * 8;
    float4 v0 = *(const float4*)(ow + i);
    float4 v1 = *(const float4*)(ow + i + 4);
    float vv[8] = {v0.x, v0.y, v0.z, v0.w, v1.x, v1.y, v1.z, v1.w};
    half8 h;
#pragma unroll
    for (int j = 0; j < 8; ++j) h[j] = (_Float16)vv[j];
    *(half8*)(owh + i) = h;
}

// ---------------- qkv GEMM, 256x256 tile ----------------
__global__ __launch_bounds__(512, 2) void k_qkv256(
    const _Float16* __restrict__ xh, const _Float16* __restrict__ wh,
    _Float16* __restrict__ qh, _Float16* __restrict__ kh, _Float16* __restrict__ vT)
{
    __shared__ __align__(16) _Float16 L[65536];   // 128 KiB ring
    // bijective XCD swizzle (nwg = 768, %8 == 0)
    const int gx = gridDim.x;
    const int nwg = gx * gridDim.y;
    const int lin = blockIdx.x + gx * blockIdx.y;
    const int wg = (lin & 7) * (nwg >> 3) + (lin >> 3);
    const int m0 = (wg % gx) * 256, n0 = (wg / gx) * 256;
    const int tid = threadIdx.x;
    floatx4 acc[8][4];
    zacc(acc);
    gemm256(xh + (size_t)m0 * 1024, wh + (size_t)n0 * 1024, 1024, L, acc, tid);

    const int lane = tid & 63, w = tid >> 6;
    const int lr = lane & 15, quad = lane >> 4;
    const int mb0 = m0 + (w >> 2) * 128 + quad * 4;
    const int nb0 = n0 + (w & 3) * 64 + lr;
    if (n0 < 1024) {            // q, scaled by 1/sqrt(1024)
#pragma unroll
        for (int mi = 0; mi < 8; ++mi)
#pragma unroll
            for (int ni = 0; ni < 4; ++ni)
#pragma unroll
                for (int r = 0; r < 4; ++r)
                    qh[(size_t)(mb0 + mi * 16 + r) * 1024 + (nb0 + ni * 16)] =
                        (_Float16)(acc[mi][ni][r] * 0.03125f);
    } else if (n0 < 2048) {     // k
#pragma unroll
        for (int mi = 0; mi < 8; ++mi)
#pragma unroll
            for (int ni = 0; ni < 4; ++ni)
#pragma unroll
                for (int r = 0; r < 4; ++r)
                    kh[(size_t)(mb0 + mi * 16 + r) * 1024 + (nb0 - 1024 + ni * 16)] =
                        (_Float16)acc[mi][ni][r];
    } else {                    // v, transposed: vT[b][e][seq]
#pragma unroll
        for (int mi = 0; mi < 8; ++mi)
#pragma unroll
            for (int ni = 0; ni < 4; ++ni) {
                int mb = mb0 + mi * 16;          // 4-aligned; tiles never cross batch
                int b = mb >> 11, ml = mb & 2047;
                int e = nb0 - 2048 + ni * 16;
                half4 pk;
#pragma unroll
                for (int r = 0; r < 4; ++r) pk[r] = (_Float16)acc[mi][ni][r];
                *(half4*)&vT[((size_t)b * 1024 + e) * 2048 + ml] = pk;
            }
    }
}

// ---------------- generic 256x256 fp16 GEMM (A,B row-major contiguous-K) ----
// EPI 0: fp16 out at C16[z*sCz + m*ldc + n]; EPI 1: fp32 out + bias
template <int EPI>
__global__ __launch_bounds__(512, 2) void k_g256(
    const _Float16* __restrict__ Ab, const _Float16* __restrict__ Bb,
    _Float16* __restrict__ C16, float* __restrict__ C32, const float* __restrict__ bias,
    int K, unsigned long long sAz, unsigned long long sBz, unsigned long long sCz, int ldc)
{
    __shared__ __align__(16) _Float16 L[65536];
    const int gx = gridDim.x, gy = gridDim.y;
    const int nwg = gx * gy * gridDim.z;        // all launches have nwg % 8 == 0
    const int lin = blockIdx.x + gx * (blockIdx.y + gy * blockIdx.z);
    const int wg = (lin & 7) * (nwg >> 3) + (lin >> 3);
    const int bx = wg % gx, by = (wg / gx) % gy, bz = wg / (gx * gy);
    const int m0 = bx * 256, n0 = by * 256;
    const int tid = threadIdx.x;
    floatx4 acc[8][4];
    zacc(acc);
    gemm256(Ab + (size_t)bz * sAz + (size_t)m0 * K,
            Bb + (size_t)bz * sBz + (size_t)n0 * K, K, L, acc, tid);

    const int lane = tid & 63, w = tid >> 6;
    const int lr = lane & 15, quad = lane >> 4;
    const int mb0 = m0 + (w >> 2) * 128 + quad * 4;
    const int nb0 = n0 + (w & 3) * 64 + lr;
#pragma unroll
    for (int mi = 0; mi < 8; ++mi)
#pragma unroll
        for (int ni = 0; ni < 4; ++ni)
#pragma unroll
            for (int r = 0; r < 4; ++r) {
                int m = mb0 + mi * 16 + r;
                int n = nb0 + ni * 16;
                if (EPI == 0)
                    C16[(size_t)bz * sCz + (size_t)m * ldc + n] = (_Float16)acc[mi][ni][r];
                else
                    C32[(size_t)m * ldc + n] = acc[mi][ni][r] + bias[n];
            }
}

// ---------------- softmax rows, fp16 in place (unchanged) ----------------
DEVI float wred_max(float v) {
#pragma unroll
    for (int o = 32; o; o >>= 1) v = fmaxf(v, __shfl_xor(v, o, 64));
    return v;
}
DEVI float wred_sum(float v) {
#pragma unroll
    for (int o = 32; o; o >>= 1) v += __shfl_xor(v, o, 64);
    return v;
}

__global__ __launch_bounds__(256) void k_softmax(_Float16* __restrict__ S) {
    const size_t row = blockIdx.x;
    _Float16* p = S + row * 2048;
    const int t = threadIdx.x;
    __shared__ float redm[4], reds[4];
    float v[8];
    float mx = -3.4e38f;
#pragma unroll
    for (int i = 0; i < 8; ++i) { v[i] = (float)p[t + i * 256]; mx = fmaxf(mx, v[i]); }
    mx = wred_max(mx);
    if ((t & 63) == 0) redm[t >> 6] = mx;
    __syncthreads();
    mx = fmaxf(fmaxf(redm[0], redm[1]), fmaxf(redm[2], redm[3]));
    float s = 0.f;
#pragma unroll
    for (int i = 0; i < 8; ++i) { v[i] = __expf(v[i] - mx); s += v[i]; }
    s = wred_sum(s);
    if ((t & 63) == 0) reds[t >> 6] = s;
    __syncthreads();
    s = reds[0] + reds[1] + reds[2] + reds[3];
    float inv = 1.0f / s;
#pragma unroll
    for (int i = 0; i < 8; ++i) p[t + i * 256] = (_Float16)(v[i] * inv);
}

// ---------------- launch ----------------
extern "C" void kernel_launch(void* const* d_in, const int* in_sizes, int n_in,
                              void* d_out, int out_size, void* d_ws, size_t ws_size,
                              hipStream_t stream) {
    const float* x  = (const float*)d_in[0];   // [8,2048,1024]
    const float* wq = (const float*)d_in[1];   // [1024,3072]
    const float* ow = (const float*)d_in[2];   // [1024,1024]
    const float* ob = (const float*)d_in[3];   // [1024]
    float* out = (float*)d_out;                // [8,2048,1024] fp32

    // workspace layout (bytes)
    char* ws = (char*)d_ws;
    _Float16* xh  = (_Float16*)(ws + 0);           // 32 MB (dead after qkv)
    _Float16* wh  = (_Float16*)(ws + 33554432);    // 6 MB  (dead after qkv)
    _Float16* S   = (_Float16*)(ws + 0);           // 64 MB [8][2048][2048] over xh+wh
    _Float16* qh  = (_Float16*)(ws + 67108864);    // 32 MB (scaled 1/32)
    _Float16* kh  = (_Float16*)(ws + 100663296);   // 32 MB
    _Float16* vT  = (_Float16*)(ws + 134217728);   // 32 MB [8][1024][2048]
    _Float16* owh = (_Float16*)(ws + 167772160);   // 2 MB
    _Float16* y   = qh;                            // qh dead after S-gemm

    if (ws_size < 180355072ull) return;  // clean fail instead of OOB corruption

    hipLaunchKernelGGL(k_cast_x, dim3(8192), dim3(256), 0, stream, x, xh);
    hipLaunchKernelGGL(k_prep_w, dim3(96, 32), dim3(256), 0, stream, wq, wh);
    hipLaunchKernelGGL(k_qkv256, dim3(64, 12), dim3(512), 0, stream, xh, wh, qh, kh, vT);
    // S = q k^T (over dead xh/wh region)
    hipLaunchKernelGGL((k_g256<0>), dim3(8, 8, 8), dim3(512), 0, stream,
                       qh, kh, S, (float*)nullptr, (const float*)nullptr,
                       1024, 2048ull * 1024, 2048ull * 1024, 2048ull * 2048, 2048);
    hipLaunchKernelGGL(k_prep_ow, dim3(512), dim3(256), 0, stream, ow, owh);
    hipLaunchKernelGGL(k_softmax, dim3(16384), dim3(256), 0, stream, S);
    // y = P V (y over dead qh region)
    hipLaunchKernelGGL((k_g256<0>), dim3(8, 4, 8), dim3(512), 0, stream,
                       S, vT, y, (float*)nullptr, (const float*)nullptr,
                       2048, 2048ull * 2048, 1024ull * 2048, 2048ull * 1024, 1024);
    // out = y ow^T + b
    hipLaunchKernelGGL((k_g256<1>), dim3(64, 4, 1), dim3(512), 0, stream,
                       y, owh, (_Float16*)nullptr, out, ob,
                       1024, 0ull, 0ull, 0ull, 1024);
}

// Round 2
// 475.375 us; speedup vs baseline: 1.0186x; 1.0186x over previous
//
#include <hip/hip_runtime.h>

typedef __attribute__((ext_vector_type(8))) _Float16 half8;
typedef __attribute__((ext_vector_type(4))) _Float16 half4;
typedef __attribute__((ext_vector_type(4))) float floatx4;

#define DEVI __device__ __forceinline__

// ---------------- async global->LDS, 16B/lane ----------------
DEVI void gload_lds16(const _Float16* g, _Float16* l) {
    __builtin_amdgcn_global_load_lds(
        (const __attribute__((address_space(1))) void*)g,
        (__attribute__((address_space(3))) void*)l, 16, 0, 0);
}

#define WAITV(N) asm volatile("s_waitcnt vmcnt(" #N ")" ::: "memory")
#define SBAR() do { __builtin_amdgcn_sched_barrier(0); __builtin_amdgcn_s_barrier(); __builtin_amdgcn_sched_barrier(0); } while (0)

// =====================================================================
// 256x256-tile GEMM, K consumed in 32-wide regions through a 4-slot LDS
// ring (4 x 32 KiB = 128 KiB). 512 threads = 8 waves (2M x 4N); each
// wave owns a 128x64 C sub-tile: acc[8][4] 16x16 frags (128 VGPR).
// Phase(g): stage region g+3 | ds_read frags of region g |
//           vmcnt(8) [region g+1 landed; 8 loads STAY in flight] |
//           s_barrier | setprio(1) 32x MFMA setprio(0) | s_barrier.
// =====================================================================
// LDS swizzle (R1 post-mortem fix): row stride is 32 halfs = 64 B = 16
// banks, so bank-start = 16*(r&1) + 4*chunk. The chunk XOR must cycle all
// 4 values over the even rows AND the odd rows of a 16-row read group:
// swz(r) = (r>>1)&3  (NOT r&3, which only hits 2 values per parity class
// -> 4-way conflict, measured 9.4M conflict-cycles in R1). With (r>>1)&3,
// a 16-lane ds_read_b128 group lands 2 lanes per bank-quad at distinct
// addresses = the same balance the measured-conflict-free 128^2 kernel had.
// Read side: frag rows are lr + 16m, and ((lr+16m)>>1)&3 == (lr>>1)&3,
// so the read offset stays one per-lane constant.

DEVI void stage_region(const _Float16* __restrict__ A, const _Float16* __restrict__ B,
                       int ldk, _Float16* lds, int g, int tid) {
    _Float16* s = lds + (g & 3) * 16384;
    const int r = tid >> 2;                    // row within 128-row half
    const int c = (tid & 3) ^ ((r >> 1) & 3);  // swizzled source chunk
    const size_t ko = (size_t)(g << 5) + (c << 3);
    gload_lds16(A + (size_t)r * ldk + ko,         s + tid * 8);
    gload_lds16(A + (size_t)(r + 128) * ldk + ko, s + 4096 + tid * 8);
    gload_lds16(B + (size_t)r * ldk + ko,         s + 8192 + tid * 8);
    gload_lds16(B + (size_t)(r + 128) * ldk + ko, s + 12288 + tid * 8);
}

template <int WN>   // 8/4/0: wait for next region, then barrier; -1: final phase
DEVI void phase(const _Float16* lds, int g, floatx4 acc[8][4],
                int arow0, int brow0, int cx)
{
    const _Float16* sa = lds + (g & 3) * 16384;
    const _Float16* sb = sa + 8192;
    half8 a[8], b[4];
#pragma unroll
    for (int ni = 0; ni < 4; ++ni)
        b[ni] = *(const half8*)&sb[(brow0 + ni * 16) * 32 + cx];
#pragma unroll
    for (int mi = 0; mi < 8; ++mi)
        a[mi] = *(const half8*)&sa[(arow0 + mi * 16) * 32 + cx];
    if constexpr (WN == 8) WAITV(8);
    else if constexpr (WN == 4) WAITV(4);
    else if constexpr (WN == 0) WAITV(0);
    if constexpr (WN >= 0) SBAR();
    __builtin_amdgcn_s_setprio(1);
#pragma unroll
    for (int mi = 0; mi < 8; ++mi)
#pragma unroll
        for (int ni = 0; ni < 4; ++ni)
            acc[mi][ni] = __builtin_amdgcn_mfma_f32_16x16x32_f16(a[mi], b[ni], acc[mi][ni], 0, 0, 0);
    __builtin_amdgcn_s_setprio(0);
    if constexpr (WN >= 0) SBAR();
}

// A: 256 rows (M) x K, row stride K; B: 256 rows (N) x K, row stride K.
DEVI void gemm256(const _Float16* __restrict__ A, const _Float16* __restrict__ B,
                  int K, _Float16* lds, floatx4 acc[8][4], int tid)
{
    const int lane = tid & 63, w = tid >> 6;
    const int lr = lane & 15, quad = lane >> 4;
    const int cx = (quad ^ ((lr >> 1) & 3)) << 3;   // matches stage swizzle
    const int arow0 = (w >> 2) * 128 + lr;
    const int brow0 = (w & 3) * 64 + lr;
    const int R = K >> 5;                       // regions of 32 K
    stage_region(A, B, K, lds, 0, tid);
    stage_region(A, B, K, lds, 1, tid);
    stage_region(A, B, K, lds, 2, tid);
    WAITV(8);                                   // region 0 landed
    SBAR();
    int g = 0;
    for (; g + 3 < R; ++g) {                    // steady: 8 loads in flight
        stage_region(A, B, K, lds, g + 3, tid);
        phase<8>(lds, g, acc, arow0, brow0, cx);
    }
    phase<4>(lds, g, acc, arow0, brow0, cx); ++g;
    phase<0>(lds, g, acc, arow0, brow0, cx); ++g;
    phase<-1>(lds, g, acc, arow0, brow0, cx);
}

DEVI void zacc(floatx4 acc[8][4]) {
    const floatx4 zf = {0.f, 0.f, 0.f, 0.f};
#pragma unroll
    for (int mi = 0; mi < 8; ++mi)
#pragma unroll
        for (int ni = 0; ni < 4; ++ni) acc[mi][ni] = zf;
}

// ---------------- prep kernels (unchanged) ----------------
__global__ __launch_bounds__(256) void k_cast_x(const float* __restrict__ x, _Float16* __restrict__ xh) {
    size_t i = ((size_t)blockIdx.x * 256 + threadIdx.x) * 8;
    float4 v0 = *(const float4*)(x + i);
    float4 v1 = *(const float4*)(x + i + 4);
    float vv[8] = {v0.x, v0.y, v0.z, v0.w, v1.x, v1.y, v1.z, v1.w};
    half8 h;
#pragma unroll
    for (int j = 0; j < 8; ++j) h[j] = (_Float16)vv[j];
    *(half8*)(xh + i) = h;
}

__global__ __launch_bounds__(256) void k_prep_w(const float* __restrict__ w, _Float16* __restrict__ wh) {
    __shared__ float tile[32][33];
    const int n0 = blockIdx.x * 32, k0 = blockIdx.y * 32;
    const int t = threadIdx.x;
#pragma unroll
    for (int it = 0; it < 4; ++it) {
        int idx = it * 256 + t;
        int kk = idx >> 5, nn = idx & 31;
        tile[kk][nn] = w[(size_t)(k0 + kk) * 3072 + n0 + nn];
    }
    __syncthreads();
#pragma unroll
    for (int it = 0; it < 4; ++it) {
        int idx = it * 256 + t;
        int nn = idx >> 5, kk = idx & 31;
        wh[(size_t)(n0 + nn) * 1024 + k0 + kk] = (_Float16)tile[kk][nn];
    }
}

__global__ __launch_bounds__(256) void k_prep_ow(const float* __restrict__ ow, _Float16* __restrict__ owh) {
    size_t i = ((size_t)blockIdx.x * 256 + threadIdx.x) * 8;
    float4 v0 = *(const float4*)(ow + i);
    float4 v1 = *(const float4*)(ow + i + 4);
    float vv[8] = {v0.x, v0.y, v0.z, v0.w, v1.x, v1.y, v1.z, v1.w};
    half8 h;
#pragma unroll
    for (int j = 0; j < 8; ++j) h[j] = (_Float16)vv[j];
    *(half8*)(owh + i) = h;
}

// ---------------- qkv GEMM, 256x256 tile ----------------
__global__ __launch_bounds__(512, 2) void k_qkv256(
    const _Float16* __restrict__ xh, const _Float16* __restrict__ wh,
    _Float16* __restrict__ qh, _Float16* __restrict__ kh, _Float16* __restrict__ vT)
{
    __shared__ __align__(16) _Float16 L[65536];   // 128 KiB ring
    // bijective XCD swizzle (nwg = 768, %8 == 0)
    const int gx = gridDim.x;
    const int nwg = gx * gridDim.y;
    const int lin = blockIdx.x + gx * blockIdx.y;
    const int wg = (lin & 7) * (nwg >> 3) + (lin >> 3);
    const int m0 = (wg % gx) * 256, n0 = (wg / gx) * 256;
    const int tid = threadIdx.x;
    floatx4 acc[8][4];
    zacc(acc);
    gemm256(xh + (size_t)m0 * 1024, wh + (size_t)n0 * 1024, 1024, L, acc, tid);

    const int lane = tid & 63, w = tid >> 6;
    const int lr = lane & 15, quad = lane >> 4;
    const int mb0 = m0 + (w >> 2) * 128 + quad * 4;
    const int nb0 = n0 + (w & 3) * 64 + lr;
    if (n0 < 1024) {            // q, scaled by 1/sqrt(1024)
#pragma unroll
        for (int mi = 0; mi < 8; ++mi)
#pragma unroll
            for (int ni = 0; ni < 4; ++ni)
#pragma unroll
                for (int r = 0; r < 4; ++r)
                    qh[(size_t)(mb0 + mi * 16 + r) * 1024 + (nb0 + ni * 16)] =
                        (_Float16)(acc[mi][ni][r] * 0.03125f);
    } else if (n0 < 2048) {     // k
#pragma unroll
        for (int mi = 0; mi < 8; ++mi)
#pragma unroll
            for (int ni = 0; ni < 4; ++ni)
#pragma unroll
                for (int r = 0; r < 4; ++r)
                    kh[(size_t)(mb0 + mi * 16 + r) * 1024 + (nb0 - 1024 + ni * 16)] =
                        (_Float16)acc[mi][ni][r];
    } else {                    // v, transposed: vT[b][e][seq]
#pragma unroll
        for (int mi = 0; mi < 8; ++mi)
#pragma unroll
            for (int ni = 0; ni < 4; ++ni) {
                int mb = mb0 + mi * 16;          // 4-aligned; tiles never cross batch
                int b = mb >> 11, ml = mb & 2047;
                int e = nb0 - 2048 + ni * 16;
                half4 pk;
#pragma unroll
                for (int r = 0; r < 4; ++r) pk[r] = (_Float16)acc[mi][ni][r];
                *(half4*)&vT[((size_t)b * 1024 + e) * 2048 + ml] = pk;
            }
    }
}

// ---------------- generic 256x256 fp16 GEMM (A,B row-major contiguous-K) ----
// EPI 0: fp16 out at C16[z*sCz + m*ldc + n]; EPI 1: fp32 out + bias
template <int EPI>
__global__ __launch_bounds__(512, 2) void k_g256(
    const _Float16* __restrict__ Ab, const _Float16* __restrict__ Bb,
    _Float16* __restrict__ C16, float* __restrict__ C32, const float* __restrict__ bias,
    int K, unsigned long long sAz, unsigned long long sBz, unsigned long long sCz, int ldc)
{
    __shared__ __align__(16) _Float16 L[65536];
    const int gx = gridDim.x, gy = gridDim.y;
    const int nwg = gx * gy * gridDim.z;        // all launches have nwg % 8 == 0
    const int lin = blockIdx.x + gx * (blockIdx.y + gy * blockIdx.z);
    const int wg = (lin & 7) * (nwg >> 3) + (lin >> 3);
    const int bx = wg % gx, by = (wg / gx) % gy, bz = wg / (gx * gy);
    const int m0 = bx * 256, n0 = by * 256;
    const int tid = threadIdx.x;
    floatx4 acc[8][4];
    zacc(acc);
    gemm256(Ab + (size_t)bz * sAz + (size_t)m0 * K,
            Bb + (size_t)bz * sBz + (size_t)n0 * K, K, L, acc, tid);

    const int lane = tid & 63, w = tid >> 6;
    const int lr = lane & 15, quad = lane >> 4;
    const int mb0 = m0 + (w >> 2) * 128 + quad * 4;
    const int nb0 = n0 + (w & 3) * 64 + lr;
#pragma unroll
    for (int mi = 0; mi < 8; ++mi)
#pragma unroll
        for (int ni = 0; ni < 4; ++ni)
#pragma unroll
            for (int r = 0; r < 4; ++r) {
                int m = mb0 + mi * 16 + r;
                int n = nb0 + ni * 16;
                if (EPI == 0)
                    C16[(size_t)bz * sCz + (size_t)m * ldc + n] = (_Float16)acc[mi][ni][r];
                else
                    C32[(size_t)m * ldc + n] = acc[mi][ni][r] + bias[n];
            }
}

// ---------------- softmax rows, fp16 in place (unchanged) ----------------
DEVI float wred_max(float v) {
#pragma unroll
    for (int o = 32; o; o >>= 1) v = fmaxf(v, __shfl_xor(v, o, 64));
    return v;
}
DEVI float wred_sum(float v) {
#pragma unroll
    for (int o = 32; o; o >>= 1) v += __shfl_xor(v, o, 64);
    return v;
}

__global__ __launch_bounds__(256) void k_softmax(_Float16* __restrict__ S) {
    const size_t row = blockIdx.x;
    _Float16* p = S + row * 2048;
    const int t = threadIdx.x;
    __shared__ float redm[4], reds[4];
    float v[8];
    float mx = -3.4e38f;
#pragma unroll
    for (int i = 0; i < 8; ++i) { v[i] = (float)p[t + i * 256]; mx = fmaxf(mx, v[i]); }
    mx = wred_max(mx);
    if ((t & 63) == 0) redm[t >> 6] = mx;
    __syncthreads();
    mx = fmaxf(fmaxf(redm[0], redm[1]), fmaxf(redm[2], redm[3]));
    float s = 0.f;
#pragma unroll
    for (int i = 0; i < 8; ++i) { v[i] = __expf(v[i] - mx); s += v[i]; }
    s = wred_sum(s);
    if ((t & 63) == 0) reds[t >> 6] = s;
    __syncthreads();
    s = reds[0] + reds[1] + reds[2] + reds[3];
    float inv = 1.0f / s;
#pragma unroll
    for (int i = 0; i < 8; ++i) p[t + i * 256] = (_Float16)(v[i] * inv);
}

// ---------------- launch ----------------
extern "C" void kernel_launch(void* const* d_in, const int* in_sizes, int n_in,
                              void* d_out, int out_size, void* d_ws, size_t ws_size,
                              hipStream_t stream) {
    const float* x  = (const float*)d_in[0];   // [8,2048,1024]
    const float* wq = (const float*)d_in[1];   // [1024,3072]
    const float* ow = (const float*)d_in[2];   // [1024,1024]
    const float* ob = (const float*)d_in[3];   // [1024]
    float* out = (float*)d_out;                // [8,2048,1024] fp32

    // workspace layout (bytes)
    char* ws = (char*)d_ws;
    _Float16* xh  = (_Float16*)(ws + 0);           // 32 MB (dead after qkv)
    _Float16* wh  = (_Float16*)(ws + 33554432);    // 6 MB  (dead after qkv)
    _Float16* S   = (_Float16*)(ws + 0);           // 64 MB [8][2048][2048] over xh+wh
    _Float16* qh  = (_Float16*)(ws + 67108864);    // 32 MB (scaled 1/32)
    _Float16* kh  = (_Float16*)(ws + 100663296);   // 32 MB
    _Float16* vT  = (_Float16*)(ws + 134217728);   // 32 MB [8][1024][2048]
    _Float16* owh = (_Float16*)(ws + 167772160);   // 2 MB
    _Float16* y   = qh;                            // qh dead after S-gemm

    if (ws_size < 180355072ull) return;  // clean fail instead of OOB corruption

    hipLaunchKernelGGL(k_cast_x, dim3(8192), dim3(256), 0, stream, x, xh);
    hipLaunchKernelGGL(k_prep_w, dim3(96, 32), dim3(256), 0, stream, wq, wh);
    hipLaunchKernelGGL(k_qkv256, dim3(64, 12), dim3(512), 0, stream, xh, wh, qh, kh, vT);
    // S = q k^T (over dead xh/wh region)
    hipLaunchKernelGGL((k_g256<0>), dim3(8, 8, 8), dim3(512), 0, stream,
                       qh, kh, S, (float*)nullptr, (const float*)nullptr,
                       1024, 2048ull * 1024, 2048ull * 1024, 2048ull * 2048, 2048);
    hipLaunchKernelGGL(k_prep_ow, dim3(512), dim3(256), 0, stream, ow, owh);
    hipLaunchKernelGGL(k_softmax, dim3(16384), dim3(256), 0, stream, S);
    // y = P V (y over dead qh region)
    hipLaunchKernelGGL((k_g256<0>), dim3(8, 4, 8), dim3(512), 0, stream,
                       S, vT, y, (float*)nullptr, (const float*)nullptr,
                       2048, 2048ull * 2048, 1024ull * 2048, 2048ull * 1024, 1024);
    // out = y ow^T + b
    hipLaunchKernelGGL((k_g256<1>), dim3(64, 4, 1), dim3(512), 0, stream,
                       y, owh, (_Float16*)nullptr, out, ob,
                       1024, 0ull, 0ull, 0ull, 1024);
}

// Round 3
// 443.266 us; speedup vs baseline: 1.0923x; 1.0724x over previous
//
#include <hip/hip_runtime.h>

typedef __attribute__((ext_vector_type(8))) _Float16 half8;
typedef __attribute__((ext_vector_type(4))) _Float16 half4;
typedef __attribute__((ext_vector_type(4))) float floatx4;

#define DEVI __device__ __forceinline__

// ---------------- async global->LDS, 16B/lane ----------------
DEVI void gload_lds16(const _Float16* g, _Float16* l) {
    __builtin_amdgcn_global_load_lds(
        (const __attribute__((address_space(1))) void*)g,
        (__attribute__((address_space(3))) void*)l, 16, 0, 0);
}

#define WAITV(N) asm volatile("s_waitcnt vmcnt(" #N ")" ::: "memory")
#define WAITL0() do { asm volatile("s_waitcnt lgkmcnt(0)" ::: "memory"); \
                      __builtin_amdgcn_sched_barrier(0); } while (0)
#define SBAR() do { __builtin_amdgcn_sched_barrier(0); __builtin_amdgcn_s_barrier(); \
                    __builtin_amdgcn_sched_barrier(0); } while (0)

// =====================================================================
// 256x256 GEMM, m201-style 8-phase schedule (R2 post-mortem rebuild).
// BK=64 K-tiles; LDS = 2 buffers x 4 units of 16KB (A-lo/A-hi/B-lo/B-hi),
// unit = 128 rows x 64 halfs. 8 waves (2M x 4N); wave reads ONE A unit
// and ONE B unit. Per tile, 4 quadrant phases of 16 MFMA each:
//   { [q0: 8 B-frag reads] + 4 A-frag reads | stage 1 unit (2 loads) |
//     [q3: vmcnt(4)] | barrier | lgkmcnt(0) | setprio(1) 16 MFMA | barrier }
// B-frags live in regs across the tile (read only at q0 -> B units free
// 3 phases early, enabling the deep stage pipeline). Stage table:
// q0: A-lo(T+1), q1: A-hi(T+1), q2: B-lo(T+2), q3: B-hi(T+2).
// Every stage-issue follows the barrier that frees its destination
// (A units free at q3 close, B units at q0 close). vmcnt(4) at q3
// retires tile T+1 fully, keeps B(T+2) in flight across the boundary.
// Row stride 64 halfs = 128 B; chunk-XOR swizzle c = p ^ (r&7)
// (geometry measured conflict-free, R0).
// =====================================================================

DEVI void stage_unit(const _Float16* __restrict__ src, int ldk, _Float16* dst, int tid) {
    const int s0 = tid, s1 = tid + 512;            // 1024 chunk-slots of 8 halfs
    const int r0 = s0 >> 3, c0 = (s0 & 7) ^ (r0 & 7);
    const int r1 = s1 >> 3, c1 = (s1 & 7) ^ (r1 & 7);
    gload_lds16(src + (size_t)r0 * ldk + c0 * 8, dst + s0 * 8);
    gload_lds16(src + (size_t)r1 * ldk + c1 * 8, dst + s1 * 8);
}

// stage unit u (0=A-lo,1=A-hi,2=B-lo,3=B-hi) of tile t. Source tile index
// clamped (valid dummy data); target buffer keeps ORIGINAL parity so tail
// stages land only in freed, never-again-read units.
DEVI void stage_u(const _Float16* __restrict__ A, const _Float16* __restrict__ B,
                  int K, int NT, _Float16* lds, int t, int u, int tid) {
    const int tt = t < NT ? t : NT - 1;
    const _Float16* sp = ((u < 2) ? A : B) + (size_t)((u & 1) * 128) * K + (size_t)tt * 64;
    stage_unit(sp, K, lds + ((t & 1) * 4 + u) * 8192, tid);
}

DEVI void gemm8p(const _Float16* __restrict__ A, const _Float16* __restrict__ B,
                 int K, _Float16* lds, floatx4 acc[8][4], int tid)
{
    const int lane = tid & 63, w = tid >> 6;
    const int wm = w >> 2, wn = w & 3;
    const int lr = lane & 15, quad = lane >> 4, xr = lr & 7;
    const int co0 = (quad ^ xr) << 3;          // kk=0: chunk quad
    const int co1 = ((4 + quad) ^ xr) << 3;    // kk=1: chunk 4+quad
    const int brow = (wn & 1) * 64;            // row base inside B unit
    const int aU = wm, bU = 2 + (wn >> 1);
    const int NT = K >> 6;

    // prologue: T0 all 4 units, B units of T1  (12 loads/thread-pair stream)
    stage_u(A, B, K, NT, lds, 0, 0, tid); stage_u(A, B, K, NT, lds, 0, 1, tid);
    stage_u(A, B, K, NT, lds, 0, 2, tid); stage_u(A, B, K, NT, lds, 0, 3, tid);
    stage_u(A, B, K, NT, lds, 1, 2, tid); stage_u(A, B, K, NT, lds, 1, 3, tid);
    WAITV(4);                                   // T0 landed; B(T1) in flight
    SBAR();

    for (int T = 0; T < NT; ++T) {
        const _Float16* ua = lds + ((T & 1) * 4 + aU) * 8192;
        const _Float16* ub = lds + ((T & 1) * 4 + bU) * 8192;
        half8 bf[4][2];
#pragma unroll
        for (int q = 0; q < 4; ++q) {
            if (q == 0) {
#pragma unroll
                for (int ni = 0; ni < 4; ++ni) {
                    bf[ni][0] = *(const half8*)&ub[(brow + ni * 16 + lr) * 64 + co0];
                    bf[ni][1] = *(const half8*)&ub[(brow + ni * 16 + lr) * 64 + co1];
                }
            }
            half8 af[2][2];
#pragma unroll
            for (int m2 = 0; m2 < 2; ++m2) {
                af[m2][0] = *(const half8*)&ua[(q * 32 + m2 * 16 + lr) * 64 + co0];
                af[m2][1] = *(const half8*)&ua[(q * 32 + m2 * 16 + lr) * 64 + co1];
            }
            if      (q == 0) stage_u(A, B, K, NT, lds, T + 1, 0, tid);
            else if (q == 1) stage_u(A, B, K, NT, lds, T + 1, 1, tid);
            else if (q == 2) stage_u(A, B, K, NT, lds, T + 2, 2, tid);
            else           { stage_u(A, B, K, NT, lds, T + 2, 3, tid); WAITV(4); }
            SBAR();
            WAITL0();
            __builtin_amdgcn_s_setprio(1);
#pragma unroll
            for (int kk = 0; kk < 2; ++kk)
#pragma unroll
                for (int m2 = 0; m2 < 2; ++m2)
#pragma unroll
                    for (int ni = 0; ni < 4; ++ni)
                        acc[2 * q + m2][ni] = __builtin_amdgcn_mfma_f32_16x16x32_f16(
                            af[m2][kk], bf[ni][kk], acc[2 * q + m2][ni], 0, 0, 0);
            __builtin_amdgcn_s_setprio(0);
            SBAR();
        }
    }
}

DEVI void zacc(floatx4 acc[8][4]) {
    const floatx4 zf = {0.f, 0.f, 0.f, 0.f};
#pragma unroll
    for (int mi = 0; mi < 8; ++mi)
#pragma unroll
        for (int ni = 0; ni < 4; ++ni) acc[mi][ni] = zf;
}

// ---------------- prep kernels (unchanged) ----------------
__global__ __launch_bounds__(256) void k_cast_x(const float* __restrict__ x, _Float16* __restrict__ xh) {
    size_t i = ((size_t)blockIdx.x * 256 + threadIdx.x) * 8;
    float4 v0 = *(const float4*)(x + i);
    float4 v1 = *(const float4*)(x + i + 4);
    float vv[8] = {v0.x, v0.y, v0.z, v0.w, v1.x, v1.y, v1.z, v1.w};
    half8 h;
#pragma unroll
    for (int j = 0; j < 8; ++j) h[j] = (_Float16)vv[j];
    *(half8*)(xh + i) = h;
}

__global__ __launch_bounds__(256) void k_prep_w(const float* __restrict__ w, _Float16* __restrict__ wh) {
    __shared__ float tile[32][33];
    const int n0 = blockIdx.x * 32, k0 = blockIdx.y * 32;
    const int t = threadIdx.x;
#pragma unroll
    for (int it = 0; it < 4; ++it) {
        int idx = it * 256 + t;
        int kk = idx >> 5, nn = idx & 31;
        tile[kk][nn] = w[(size_t)(k0 + kk) * 3072 + n0 + nn];
    }
    __syncthreads();
#pragma unroll
    for (int it = 0; it < 4; ++it) {
        int idx = it * 256 + t;
        int nn = idx >> 5, kk = idx & 31;
        wh[(size_t)(n0 + nn) * 1024 + k0 + kk] = (_Float16)tile[kk][nn];
    }
}

__global__ __launch_bounds__(256) void k_prep_ow(const float* __restrict__ ow, _Float16* __restrict__ owh) {
    size_t i = ((size_t)blockIdx.x * 256 + threadIdx.x) * 8;
    float4 v0 = *(const float4*)(ow + i);
    float4 v1 = *(const float4*)(ow + i + 4);
    float vv[8] = {v0.x, v0.y, v0.z, v0.w, v1.x, v1.y, v1.z, v1.w};
    half8 h;
#pragma unroll
    for (int j = 0; j < 8; ++j) h[j] = (_Float16)vv[j];
    *(half8*)(owh + i) = h;
}

// ---------------- qkv GEMM, 256x256 tile ----------------
__global__ __launch_bounds__(512, 2) void k_qkv256(
    const _Float16* __restrict__ xh, const _Float16* __restrict__ wh,
    _Float16* __restrict__ qh, _Float16* __restrict__ kh, _Float16* __restrict__ vT)
{
    __shared__ __align__(16) _Float16 L[65536];   // 128 KiB
    // bijective XCD swizzle (nwg = 768, %8 == 0)
    const int gx = gridDim.x;
    const int nwg = gx * gridDim.y;
    const int lin = blockIdx.x + gx * blockIdx.y;
    const int wg = (lin & 7) * (nwg >> 3) + (lin >> 3);
    const int m0 = (wg % gx) * 256, n0 = (wg / gx) * 256;
    const int tid = threadIdx.x;
    floatx4 acc[8][4];
    zacc(acc);
    gemm8p(xh + (size_t)m0 * 1024, wh + (size_t)n0 * 1024, 1024, L, acc, tid);

    const int lane = tid & 63, w = tid >> 6;
    const int lr = lane & 15, quad = lane >> 4;
    const int mb0 = m0 + (w >> 2) * 128 + quad * 4;
    const int nb0 = n0 + (w & 3) * 64 + lr;
    if (n0 < 1024) {            // q, scaled by 1/sqrt(1024)
#pragma unroll
        for (int mi = 0; mi < 8; ++mi)
#pragma unroll
            for (int ni = 0; ni < 4; ++ni)
#pragma unroll
                for (int r = 0; r < 4; ++r)
                    qh[(size_t)(mb0 + mi * 16 + r) * 1024 + (nb0 + ni * 16)] =
                        (_Float16)(acc[mi][ni][r] * 0.03125f);
    } else if (n0 < 2048) {     // k
#pragma unroll
        for (int mi = 0; mi < 8; ++mi)
#pragma unroll
            for (int ni = 0; ni < 4; ++ni)
#pragma unroll
                for (int r = 0; r < 4; ++r)
                    kh[(size_t)(mb0 + mi * 16 + r) * 1024 + (nb0 - 1024 + ni * 16)] =
                        (_Float16)acc[mi][ni][r];
    } else {                    // v, transposed: vT[b][e][seq]
#pragma unroll
        for (int mi = 0; mi < 8; ++mi)
#pragma unroll
            for (int ni = 0; ni < 4; ++ni) {
                int mb = mb0 + mi * 16;          // 4-aligned; tiles never cross batch
                int b = mb >> 11, ml = mb & 2047;
                int e = nb0 - 2048 + ni * 16;
                half4 pk;
#pragma unroll
                for (int r = 0; r < 4; ++r) pk[r] = (_Float16)acc[mi][ni][r];
                *(half4*)&vT[((size_t)b * 1024 + e) * 2048 + ml] = pk;
            }
    }
}

// ---------------- generic 256x256 fp16 GEMM (A,B row-major contiguous-K) ----
// EPI 0: fp16 out at C16[z*sCz + m*ldc + n]; EPI 1: fp32 out + bias
template <int EPI>
__global__ __launch_bounds__(512, 2) void k_g256(
    const _Float16* __restrict__ Ab, const _Float16* __restrict__ Bb,
    _Float16* __restrict__ C16, float* __restrict__ C32, const float* __restrict__ bias,
    int K, unsigned long long sAz, unsigned long long sBz, unsigned long long sCz, int ldc)
{
    __shared__ __align__(16) _Float16 L[65536];
    const int gx = gridDim.x, gy = gridDim.y;
    const int nwg = gx * gy * gridDim.z;        // all launches have nwg % 8 == 0
    const int lin = blockIdx.x + gx * (blockIdx.y + gy * blockIdx.z);
    const int wg = (lin & 7) * (nwg >> 3) + (lin >> 3);
    const int bx = wg % gx, by = (wg / gx) % gy, bz = wg / (gx * gy);
    const int m0 = bx * 256, n0 = by * 256;
    const int tid = threadIdx.x;
    floatx4 acc[8][4];
    zacc(acc);
    gemm8p(Ab + (size_t)bz * sAz + (size_t)m0 * K,
           Bb + (size_t)bz * sBz + (size_t)n0 * K, K, L, acc, tid);

    const int lane = tid & 63, w = tid >> 6;
    const int lr = lane & 15, quad = lane >> 4;
    const int mb0 = m0 + (w >> 2) * 128 + quad * 4;
    const int nb0 = n0 + (w & 3) * 64 + lr;
#pragma unroll
    for (int mi = 0; mi < 8; ++mi)
#pragma unroll
        for (int ni = 0; ni < 4; ++ni)
#pragma unroll
            for (int r = 0; r < 4; ++r) {
                int m = mb0 + mi * 16 + r;
                int n = nb0 + ni * 16;
                if (EPI == 0)
                    C16[(size_t)bz * sCz + (size_t)m * ldc + n] = (_Float16)acc[mi][ni][r];
                else
                    C32[(size_t)m * ldc + n] = acc[mi][ni][r] + bias[n];
            }
}

// ---------------- softmax rows, fp16 in place (unchanged) ----------------
DEVI float wred_max(float v) {
#pragma unroll
    for (int o = 32; o; o >>= 1) v = fmaxf(v, __shfl_xor(v, o, 64));
    return v;
}
DEVI float wred_sum(float v) {
#pragma unroll
    for (int o = 32; o; o >>= 1) v += __shfl_xor(v, o, 64);
    return v;
}

__global__ __launch_bounds__(256) void k_softmax(_Float16* __restrict__ S) {
    const size_t row = blockIdx.x;
    _Float16* p = S + row * 2048;
    const int t = threadIdx.x;
    __shared__ float redm[4], reds[4];
    float v[8];
    float mx = -3.4e38f;
#pragma unroll
    for (int i = 0; i < 8; ++i) { v[i] = (float)p[t + i * 256]; mx = fmaxf(mx, v[i]); }
    mx = wred_max(mx);
    if ((t & 63) == 0) redm[t >> 6] = mx;
    __syncthreads();
    mx = fmaxf(fmaxf(redm[0], redm[1]), fmaxf(redm[2], redm[3]));
    float s = 0.f;
#pragma unroll
    for (int i = 0; i < 8; ++i) { v[i] = __expf(v[i] - mx); s += v[i]; }
    s = wred_sum(s);
    if ((t & 63) == 0) reds[t >> 6] = s;
    __syncthreads();
    s = reds[0] + reds[1] + reds[2] + reds[3];
    float inv = 1.0f / s;
#pragma unroll
    for (int i = 0; i < 8; ++i) p[t + i * 256] = (_Float16)(v[i] * inv);
}

// ---------------- launch ----------------
extern "C" void kernel_launch(void* const* d_in, const int* in_sizes, int n_in,
                              void* d_out, int out_size, void* d_ws, size_t ws_size,
                              hipStream_t stream) {
    const float* x  = (const float*)d_in[0];   // [8,2048,1024]
    const float* wq = (const float*)d_in[1];   // [1024,3072]
    const float* ow = (const float*)d_in[2];   // [1024,1024]
    const float* ob = (const float*)d_in[3];   // [1024]
    float* out = (float*)d_out;                // [8,2048,1024] fp32

    // workspace layout (bytes)
    char* ws = (char*)d_ws;
    _Float16* xh  = (_Float16*)(ws + 0);           // 32 MB (dead after qkv)
    _Float16* wh  = (_Float16*)(ws + 33554432);    // 6 MB  (dead after qkv)
    _Float16* S   = (_Float16*)(ws + 0);           // 64 MB [8][2048][2048] over xh+wh
    _Float16* qh  = (_Float16*)(ws + 67108864);    // 32 MB (scaled 1/32)
    _Float16* kh  = (_Float16*)(ws + 100663296);   // 32 MB
    _Float16* vT  = (_Float16*)(ws + 134217728);   // 32 MB [8][1024][2048]
    _Float16* owh = (_Float16*)(ws + 167772160);   // 2 MB
    _Float16* y   = qh;                            // qh dead after S-gemm

    if (ws_size < 180355072ull) return;  // clean fail instead of OOB corruption

    hipLaunchKernelGGL(k_cast_x, dim3(8192), dim3(256), 0, stream, x, xh);
    hipLaunchKernelGGL(k_prep_w, dim3(96, 32), dim3(256), 0, stream, wq, wh);
    hipLaunchKernelGGL(k_qkv256, dim3(64, 12), dim3(512), 0, stream, xh, wh, qh, kh, vT);
    // S = q k^T (over dead xh/wh region)
    hipLaunchKernelGGL((k_g256<0>), dim3(8, 8, 8), dim3(512), 0, stream,
                       qh, kh, S, (float*)nullptr, (const float*)nullptr,
                       1024, 2048ull * 1024, 2048ull * 1024, 2048ull * 2048, 2048);
    hipLaunchKernelGGL(k_prep_ow, dim3(512), dim3(256), 0, stream, ow, owh);
    hipLaunchKernelGGL(k_softmax, dim3(16384), dim3(256), 0, stream, S);
    // y = P V (y over dead qh region)
    hipLaunchKernelGGL((k_g256<0>), dim3(8, 4, 8), dim3(512), 0, stream,
                       S, vT, y, (float*)nullptr, (const float*)nullptr,
                       2048, 2048ull * 2048, 1024ull * 2048, 2048ull * 1024, 1024);
    // out = y ow^T + b
    hipLaunchKernelGGL((k_g256<1>), dim3(64, 4, 1), dim3(512), 0, stream,
                       y, owh, (_Float16*)nullptr, out, ob,
                       1024, 0ull, 0ull, 0ull, 1024);
}